// Round 7
// baseline (1437.341 us; speedup 1.0000x reference)
//
#include <hip/hip_runtime.h>

#define SEQ 1024
#define BN  512
#define NT  64
#define CPB 4            // chains (batch items) per block/wave
#define NBLK (BN / CPB)  // 128 blocks
#define SUP 68           // su row pad (bank-staggers the 4 broadcast groups)

typedef float f4 __attribute__((ext_vector_type(4)));

__global__ void zero_out_kernel(float* o) { o[0] = 0.0f; }

__device__ __forceinline__ f4 expf4(f4 v) {
    return (f4){__expf(v.x), __expf(v.y), __expf(v.z), __expf(v.w)};
}
// acc += scalar * vec  (2x v_pk_fma_f32)
__device__ __forceinline__ f4 fma4s(float s, f4 e, f4 a) {
    f4 sv = {s, s, s, s};
    return __builtin_elementwise_fma(sv, e, a);
}

#define RPT64(M) \
  M(0) M(1) M(2) M(3) M(4) M(5) M(6) M(7) M(8) M(9) \
  M(10) M(11) M(12) M(13) M(14) M(15) M(16) M(17) M(18) M(19) \
  M(20) M(21) M(22) M(23) M(24) M(25) M(26) M(27) M(28) M(29) \
  M(30) M(31) M(32) M(33) M(34) M(35) M(36) M(37) M(38) M(39) \
  M(40) M(41) M(42) M(43) M(44) M(45) M(46) M(47) M(48) M(49) \
  M(50) M(51) M(52) M(53) M(54) M(55) M(56) M(57) M(58) M(59) \
  M(60) M(61) M(62) M(63)

// E[i] = {exp(T[i][jb..jb+3])}: 64 NAMED f4 = 256 VGPRs, identical across
// the 4 lane-groups (shared). Static access only.
#define EDECL(i) const f4 E##i = expf4(*(const f4*)(trans + (i) * NT + jb));

// chunk k: r = broadcast u[4k..4k+3] of OWN chain; 4 scalar-x-f4 FMAs
#define CHUNK(k, i0, i1, i2, i3, Aa, Bb, Cc, Dd) {            \
    f4 r = *(const f4*)(suq + 4 * (k));                       \
    Aa = fma4s(r.x, E##i0, Aa);                               \
    Bb = fma4s(r.y, E##i1, Bb);                               \
    Cc = fma4s(r.z, E##i2, Cc);                               \
    Dd = fma4s(r.w, E##i3, Dd);                               \
  }

extern "C" __global__ __launch_bounds__(64, 1)
void crf_kernel(const float* __restrict__ emis,
                const int*   __restrict__ tags,
                const int*   __restrict__ mask,
                const float* __restrict__ startT,
                const float* __restrict__ endT,
                const float* __restrict__ trans,
                float* __restrict__ out)
{
    const int bid  = blockIdx.x;
    const int lane = threadIdx.x;
    const int q    = lane >> 4;        // chain index within wave
    const int c    = lane & 15;        // column-group
    const int jb   = 4 * c;            // first owned column
    const int bq   = bid * CPB + q;    // batch item of this lane's chain

    __shared__ __align__(16) float su[CPB * SUP];      // 4 padded u vectors
    __shared__ __align__(16) float strans[NT * SUP];   // Trow lookups (pad 68)
    __shared__ int spkI[SEQ * CPB];                    // (tag|mask<<16), t*4+q

    float* suq = &su[q * SUP];

    // ---- one-time staging (single wave, in-order DS pipe, no barriers) ----
    for (int i = 0; i < NT; ++i)
        strans[i * SUP + lane] = trans[i * NT + lane];
    for (int idx = lane; idx < SEQ * CPB; idx += 64) {
        int t  = idx >> 2, qq = idx & 3;
        int bb = bid * CPB + qq;
        spkI[idx] = (tags[t * BN + bb] & 0xFFFF) | (mask[t * BN + bb] << 16);
    }
    __threadfence_block();

    // ---- E in registers: 64 named f4 (256 VGPRs) ----
    RPT64(EDECL)

    // ---- t = 0 init (per lane-group) ----
    f4 em0    = *(const f4*)(emis + (0 * BN + bq) * NT + jb);
    f4 st4    = *(const f4*)(startT + jb);
    f4 alpha0 = st4 + em0;
    // per-chain anchor = group leader's column-0 alpha
    float M = __shfl(alpha0.x, lane & 48, 64);
    f4 u = expf4(alpha0 - (f4){M, M, M, M});

    int   pk0 = spkI[0 * CPB + q];
    int   tgv = pk0 & 0xFFFF;          // current tag (per chain)
    f4 score = {0.f, 0.f, 0.f, 0.f};
    {
        int d = tgv - jb;
        score.x = (d == 0) ? alpha0.x : 0.f;
        score.y = (d == 1) ? alpha0.y : 0.f;
        score.z = (d == 2) ? alpha0.z : 0.f;
        score.w = (d == 3) ? alpha0.w : 0.f;
    }
    int ltv  = tgv;
    int esum = 0;

    *(f4*)(suq + jb) = u;              // publish u_0

    int pkC   = spkI[1 * CPB + q];
    f4  TrowC = *(const f4*)(&strans[tgv * SUP + jb]);

    // depth-4 emission prefetch (the only loop vmem)
    f4 emA = *(const f4*)(emis + (1 * BN + bq) * NT + jb);
    f4 emB = *(const f4*)(emis + (2 * BN + bq) * NT + jb);
    f4 emC = *(const f4*)(emis + (3 * BN + bq) * NT + jb);
    f4 emD = *(const f4*)(emis + (4 * BN + bq) * NT + jb);

    #pragma unroll 1
    for (int t = 1; t < SEQ; ++t) {
        const f4 em_t = emA;
        emA = emB; emB = emC; emC = emD;
        int tn = t + 4; if (tn > SEQ - 1) tn = SEQ - 1;
        emD = *(const f4*)(emis + (tn * BN + bq) * NT + jb);

        const int pk   = pkC;              // prefetched last iteration
        const int tg_t = pk & 0xFFFF;
        const int mk_t = pk >> 16;         // 0/1, group-uniform
        const f4  Trow = TrowC;

        const f4 w = expf4(em_t);          // off the u-chain

        // ---- shared broadcast: 16 b128 reads serve all 4 chains ----
        f4 a0 = {0,0,0,0}, a1 = {0,0,0,0}, a2 = {0,0,0,0}, a3 = {0,0,0,0};
        f4 a4 = {0,0,0,0}, a5 = {0,0,0,0}, a6 = {0,0,0,0}, a7 = {0,0,0,0};
        CHUNK( 0,  0,  1,  2,  3, a0, a1, a2, a3)
        CHUNK( 1,  4,  5,  6,  7, a4, a5, a6, a7)
        CHUNK( 2,  8,  9, 10, 11, a0, a1, a2, a3)
        CHUNK( 3, 12, 13, 14, 15, a4, a5, a6, a7)
        CHUNK( 4, 16, 17, 18, 19, a0, a1, a2, a3)
        CHUNK( 5, 20, 21, 22, 23, a4, a5, a6, a7)
        CHUNK( 6, 24, 25, 26, 27, a0, a1, a2, a3)
        CHUNK( 7, 28, 29, 30, 31, a4, a5, a6, a7)
        CHUNK( 8, 32, 33, 34, 35, a0, a1, a2, a3)
        CHUNK( 9, 36, 37, 38, 39, a4, a5, a6, a7)
        CHUNK(10, 40, 41, 42, 43, a0, a1, a2, a3)
        CHUNK(11, 44, 45, 46, 47, a4, a5, a6, a7)
        CHUNK(12, 48, 49, 50, 51, a0, a1, a2, a3)
        CHUNK(13, 52, 53, 54, 55, a4, a5, a6, a7)
        CHUNK(14, 56, 57, 58, 59, a0, a1, a2, a3)
        CHUNK(15, 60, 61, 62, 63, a4, a5, a6, a7)

        // next-iter control prefetch: queues behind the chunk reads
        int tp = t + 1; if (tp > SEQ - 1) tp = SEQ - 1;
        pkC   = spkI[tp * CPB + q];
        TrowC = *(const f4*)(&strans[tg_t * SUP + jb]);

        const f4 s  = ((a0 + a1) + (a2 + a3)) + ((a4 + a5) + (a6 + a7));
        const f4 sw = s * w;

        // per-lane (group-uniform) select; no wave-uniform branch possible
        u = mk_t ? sw : u;

        // numerator (off-chain): owner-slot conditional adds
        {
            int d = tg_t - jb;
            score.x += (mk_t && d == 0) ? em_t.x + Trow.x : 0.f;
            score.y += (mk_t && d == 1) ? em_t.y + Trow.y : 0.f;
            score.z += (mk_t && d == 2) ? em_t.z + Trow.z : 0.f;
            score.w += (mk_t && d == 3) ? em_t.w + Trow.w : 0.f;
        }
        ltv = mk_t ? tg_t : ltv;

        if ((t & 3) == 0) {                // deferred exact renorm, per chain
            int b0  = __builtin_amdgcn_readlane(__float_as_int(u.x),  0);
            int b16 = __builtin_amdgcn_readlane(__float_as_int(u.x), 16);
            int b32 = __builtin_amdgcn_readlane(__float_as_int(u.x), 32);
            int b48 = __builtin_amdgcn_readlane(__float_as_int(u.x), 48);
            int bl  = (lane & 32) ? ((lane & 16) ? b48 : b32)
                                  : ((lane & 16) ? b16 : b0);
            int e   = (bl >> 23) & 255;
            int sh  = 127 - e;
            u.x = ldexpf(u.x, sh); u.y = ldexpf(u.y, sh);
            u.z = ldexpf(u.z, sh); u.w = ldexpf(u.w, sh);
            esum += e - 127;
        }

        *(f4*)(suq + jb) = u;              // publish for t+1 (in-order pipe)
    }

    // ---- epilogue: per-chain reduction within each 16-lane group ----
    f4 endv = *(const f4*)(endT + jb);
    {
        int d = ltv - jb;
        score.x += (d == 0) ? endv.x : 0.f;
        score.y += (d == 1) ? endv.y : 0.f;
        score.z += (d == 2) ? endv.z : 0.f;
        score.w += (d == 3) ? endv.w : 0.f;
    }
    f4 vv = u * expf4(endv);
    float v  = (vv.x + vv.y) + (vv.z + vv.w);
    float sp = (score.x + score.y) + (score.z + score.w);
    #pragma unroll
    for (int off = 8; off > 0; off >>= 1) {   // stays within 16-lane group
        v  += __shfl_xor(v,  off, 64);
        sp += __shfl_xor(sp, off, 64);
    }
    if ((lane & 15) == 0) {
        float denom = M + (float)esum * 0.69314718055994531f + __logf(v);
        atomicAdd(out, sp - denom);
    }
}

extern "C" void kernel_launch(void* const* d_in, const int* in_sizes, int n_in,
                              void* d_out, int out_size, void* d_ws, size_t ws_size,
                              hipStream_t stream)
{
    const float* emis   = (const float*)d_in[0];
    const int*   tags   = (const int*)  d_in[1];
    const int*   mask   = (const int*)  d_in[2];
    const float* startT = (const float*)d_in[3];
    const float* endT   = (const float*)d_in[4];
    const float* trans  = (const float*)d_in[5];
    float* out = (float*)d_out;

    zero_out_kernel<<<1, 1, 0, stream>>>(out);
    crf_kernel<<<dim3(NBLK), dim3(NT), 0, stream>>>(emis, tags, mask,
                                                    startT, endT, trans, out);
}

// Round 8
// 395.263 us; speedup vs baseline: 3.6364x; 3.6364x over previous
//
#include <hip/hip_runtime.h>

#define SEQ  1024
#define BN   512
#define NT   64
#define HALF 512   // forward: t=1..512 ; backward: t=1023..513

__global__ void zero_out_kernel(float* o) { o[0] = 0.0f; }

// lane-broadcast: v_readlane_b32 -> SGPR, feeds v_fmac_f32 (1 SGPR src legal)
__device__ __forceinline__ float rlf(float v, int l) {
    return __int_as_float(__builtin_amdgcn_readlane(__float_as_int(v), l));
}

// 8 broadcasts + 8 FMAs into 8 independent chains (depth 8 across groups)
#define G8(SRC, TP, i0,i1,i2,i3,i4,i5,i6,i7) {     \
    a0 = fmaf(rlf(SRC,i0), TP##i0, a0);            \
    a1 = fmaf(rlf(SRC,i1), TP##i1, a1);            \
    a2 = fmaf(rlf(SRC,i2), TP##i2, a2);            \
    a3 = fmaf(rlf(SRC,i3), TP##i3, a3);            \
    a4 = fmaf(rlf(SRC,i4), TP##i4, a4);            \
    a5 = fmaf(rlf(SRC,i5), TP##i5, a5);            \
    a6 = fmaf(rlf(SRC,i6), TP##i6, a6);            \
    a7 = fmaf(rlf(SRC,i7), TP##i7, a7);            \
  }
#define GALL(SRC, TP)                              \
    G8(SRC, TP,  0, 1, 2, 3, 4, 5, 6, 7)           \
    G8(SRC, TP,  8, 9,10,11,12,13,14,15)           \
    G8(SRC, TP, 16,17,18,19,20,21,22,23)           \
    G8(SRC, TP, 24,25,26,27,28,29,30,31)           \
    G8(SRC, TP, 32,33,34,35,36,37,38,39)           \
    G8(SRC, TP, 40,41,42,43,44,45,46,47)           \
    G8(SRC, TP, 48,49,50,51,52,53,54,55)           \
    G8(SRC, TP, 56,57,58,59,60,61,62,63)

#define RPT64(M) \
  M(0) M(1) M(2) M(3) M(4) M(5) M(6) M(7) M(8) M(9) \
  M(10) M(11) M(12) M(13) M(14) M(15) M(16) M(17) M(18) M(19) \
  M(20) M(21) M(22) M(23) M(24) M(25) M(26) M(27) M(28) M(29) \
  M(30) M(31) M(32) M(33) M(34) M(35) M(36) M(37) M(38) M(39) \
  M(40) M(41) M(42) M(43) M(44) M(45) M(46) M(47) M(48) M(49) \
  M(50) M(51) M(52) M(53) M(54) M(55) M(56) M(57) M(58) M(59) \
  M(60) M(61) M(62) M(63)

extern "C" __global__ __launch_bounds__(128, 1)
void crf_kernel(const float* __restrict__ emis,
                const int*   __restrict__ tags,
                const int*   __restrict__ mask,
                const float* __restrict__ startT,
                const float* __restrict__ endT,
                const float* __restrict__ trans,
                float* __restrict__ out)
{
    const int b    = blockIdx.x;      // one batch item per block
    const int tid  = threadIdx.x;
    const int lane = tid & 63;
    const int wv   = tid >> 6;        // 0 = forward, 1 = backward

    __shared__ __align__(16) float strans[NT * NT];  // numerator Trow lookups
    __shared__ int   spk[SEQ];                       // tag | mask<<16
    __shared__ float suF[NT], suB[NT];               // final u / v vectors
    __shared__ float scal[4];                        // spF, M_f, spB
    __shared__ int   icom[4];                        // esumF, ltF, esumB, ltB

    // ---- one-time staging, all 128 threads ----
    {
        const float4* t4 = (const float4*)trans;
        float4* s4 = (float4*)strans;
        #pragma unroll
        for (int k = 0; k < 8; ++k)
            s4[k * 128 + tid] = t4[k * 128 + tid];
    }
    #pragma unroll
    for (int c = 0; c < SEQ / 128; ++c) {
        int t = c * 128 + tid;
        spk[t] = (tags[t * BN + b] & 0xFFFF) | (mask[t * BN + b] << 16);
    }
    __syncthreads();

    if (wv == 0) {
        // ================= FORWARD: alpha scan, t = 1..HALF =================
        // E columns: EF_i[lane] = exp(T[i][lane])  (64 named VGPRs)
#define EFD(i) const float EF##i = __expf(trans[(i) * NT + lane]);
        RPT64(EFD)
#undef EFD
        float em0    = emis[(0 * BN + b) * NT + lane];
        int   tg_p   = spk[0] & 0xFFFF;
        float alpha0 = startT[lane] + em0;
        float M = __int_as_float(__builtin_amdgcn_readfirstlane(__float_as_int(alpha0)));
        float u = __expf(alpha0 - M);
        float score = (lane == tg_p) ? alpha0 : 0.0f;
        int   lt    = tg_p;
        int   esum  = 0;

        int   pkC   = spk[1];
        float TrowC = strans[tg_p * NT + lane];

        float emA = emis[(1 * BN + b) * NT + lane];
        float emB = emis[(2 * BN + b) * NT + lane];
        float emC = emis[(3 * BN + b) * NT + lane];
        float emD = emis[(4 * BN + b) * NT + lane];

        #pragma unroll 4
        for (int t = 1; t <= HALF; ++t) {
            const float em_t = emA;
            emA = emB; emB = emC; emC = emD;
            int tn = t + 4; if (tn > HALF) tn = HALF;
            emD = emis[(tn * BN + b) * NT + lane];

            const int   pk   = pkC;
            const int   tg_t = pk & 0xFFFF;
            const int   mk_t = pk >> 16;
            const float Trow = TrowC;

            pkC   = spk[t + 1];                 // spk[HALF+1] exists
            TrowC = strans[tg_t * NT + lane];

            const float w = __expf(em_t);       // off the u-chain

            float a0=0.f,a1=0.f,a2=0.f,a3=0.f,a4=0.f,a5=0.f,a6=0.f,a7=0.f;
            GALL(u, EF)
            const float s  = ((a0+a1)+(a2+a3)) + ((a4+a5)+(a6+a7));
            const float sw = s * w;

            if (mk_t) {                          // wave-uniform
                u = sw;
                if (lane == tg_t) score += em_t + Trow;
                lt = tg_t;
            }
            if ((t & 3) == 0) {                  // deferred exact renorm
                int e = (__builtin_amdgcn_readfirstlane(__float_as_int(u)) >> 23) & 255;
                u = ldexpf(u, 127 - e);
                esum += e - 127;
            }
        }

        float sp = score;
        #pragma unroll
        for (int off = 32; off > 0; off >>= 1) sp += __shfl_xor(sp, off, 64);
        suF[lane] = u;
        if (lane == 0) { scal[0] = sp; scal[1] = M; icom[0] = esum; icom[1] = lt; }
    } else {
        // ================ BACKWARD: v scan, t = 1023..HALF+1 ================
        // v_{t-1}[i] = mk_t ? sum_j E[i][j] * (w_t[j] v_t[j]) : v_t[i]
        // E rows: EB_j[lane] = exp(T[lane][j])  (64 named VGPRs)
#define EBD(j) const float EB##j = __expf(trans[lane * NT + (j)]);
        RPT64(EBD)
#undef EBD
        float v = __expf(endT[lane]);           // v_{1023} = f
        float score = 0.0f;
        int   lt = -1;                          // -1 = no masked step seen
        int   esum = 0;

        int pkA = spk[SEQ - 1];                 // spk[t]   for current t
        int pkN = spk[SEQ - 2];                 // spk[t-1] (gives tg_{t-1})

        float emA = emis[((SEQ - 1) * BN + b) * NT + lane];
        float emB = emis[((SEQ - 2) * BN + b) * NT + lane];
        float emC = emis[((SEQ - 3) * BN + b) * NT + lane];
        float emD = emis[((SEQ - 4) * BN + b) * NT + lane];

        #pragma unroll 4
        for (int t = SEQ - 1; t > HALF; --t) {
            const float em_t = emA;
            emA = emB; emB = emC; emC = emD;
            int tn = t - 4; if (tn < HALF + 1) tn = HALF + 1;
            emD = emis[(tn * BN + b) * NT + lane];

            const int tgc = pkA & 0xFFFF;
            const int mk  = pkA >> 16;
            const int tgp = pkN & 0xFFFF;                // tg_{t-1}
            const float Trow = strans[tgp * NT + lane];  // early-issue, late use

            pkA = pkN;                                   // prefetch t-1
            int t2 = t - 2; if (t2 < 0) t2 = 0;
            pkN = spk[t2];

            const float w = __expf(em_t);                // off-chain
            const float y = w * v;                       // on-chain, 1 op

            float a0=0.f,a1=0.f,a2=0.f,a3=0.f,a4=0.f,a5=0.f,a6=0.f,a7=0.f;
            GALL(y, EB)
            const float s = ((a0+a1)+(a2+a3)) + ((a4+a5)+(a6+a7));

            if (mk) {                            // wave-uniform
                v = s;
                if (lane == tgc) score += em_t + Trow;
                if (lt < 0) lt = tgc;            // first seen = highest t
            }
            if ((t & 3) == 0) {                  // deferred exact renorm
                int e = (__builtin_amdgcn_readfirstlane(__float_as_int(v)) >> 23) & 255;
                v = ldexpf(v, 127 - e);
                esum += e - 127;
            }
        }

        float sp = score;
        #pragma unroll
        for (int off = 32; off > 0; off >>= 1) sp += __shfl_xor(sp, off, 64);
        suB[lane] = v;
        if (lane == 0) { scal[2] = sp; icom[2] = esum; icom[3] = lt; }
    }

    __syncthreads();

    // ---- combine on wave 0: denom = M_f + (esF+esB)*ln2 + log(u . v) ----
    if (wv == 0) {
        float prod = suF[lane] * suB[lane];
        #pragma unroll
        for (int off = 32; off > 0; off >>= 1) prod += __shfl_xor(prod, off, 64);
        if (lane == 0) {
            int   ltB = icom[3];
            int   lt  = (ltB >= 0) ? ltB : icom[1];
            float sc  = scal[0] + scal[2] + endT[lt];
            float denom = scal[1]
                        + (float)(icom[0] + icom[2]) * 0.69314718055994531f
                        + __logf(prod);
            atomicAdd(out, sc - denom);
        }
    }
}

extern "C" void kernel_launch(void* const* d_in, const int* in_sizes, int n_in,
                              void* d_out, int out_size, void* d_ws, size_t ws_size,
                              hipStream_t stream)
{
    const float* emis   = (const float*)d_in[0];
    const int*   tags   = (const int*)  d_in[1];
    const int*   mask   = (const int*)  d_in[2];
    const float* startT = (const float*)d_in[3];
    const float* endT   = (const float*)d_in[4];
    const float* trans  = (const float*)d_in[5];
    float* out = (float*)d_out;

    zero_out_kernel<<<1, 1, 0, stream>>>(out);
    crf_kernel<<<dim3(BN), dim3(128), 0, stream>>>(emis, tags, mask,
                                                   startT, endT, trans, out);
}

// Round 11
// 321.563 us; speedup vs baseline: 4.4699x; 1.2292x over previous
//
#include <hip/hip_runtime.h>

#define SEQ  1024
#define BN   512
#define NT   64
#define HALF 512   // forward: t=1..512 ; backward: t=1023..513

__global__ void zero_out_kernel(float* o) { o[0] = 0.0f; }

// lane-broadcast: v_readlane_b32 -> SGPR, feeds v_fmac_f32 (1 SGPR src legal)
__device__ __forceinline__ float rlf(float v, int l) {
    return __int_as_float(__builtin_amdgcn_readlane(__float_as_int(v), l));
}

// 8 broadcasts + 8 FMAs into 8 independent chains (depth 8 across groups)
#define G8(SRC, TP, i0,i1,i2,i3,i4,i5,i6,i7) {     \
    a0 = fmaf(rlf(SRC,i0), TP##i0, a0);            \
    a1 = fmaf(rlf(SRC,i1), TP##i1, a1);            \
    a2 = fmaf(rlf(SRC,i2), TP##i2, a2);            \
    a3 = fmaf(rlf(SRC,i3), TP##i3, a3);            \
    a4 = fmaf(rlf(SRC,i4), TP##i4, a4);            \
    a5 = fmaf(rlf(SRC,i5), TP##i5, a5);            \
    a6 = fmaf(rlf(SRC,i6), TP##i6, a6);            \
    a7 = fmaf(rlf(SRC,i7), TP##i7, a7);            \
  }
#define GALL(SRC, TP)                              \
    G8(SRC, TP,  0, 1, 2, 3, 4, 5, 6, 7)           \
    G8(SRC, TP,  8, 9,10,11,12,13,14,15)           \
    G8(SRC, TP, 16,17,18,19,20,21,22,23)           \
    G8(SRC, TP, 24,25,26,27,28,29,30,31)           \
    G8(SRC, TP, 32,33,34,35,36,37,38,39)           \
    G8(SRC, TP, 40,41,42,43,44,45,46,47)           \
    G8(SRC, TP, 48,49,50,51,52,53,54,55)           \
    G8(SRC, TP, 56,57,58,59,60,61,62,63)

#define RPT64(M) \
  M(0) M(1) M(2) M(3) M(4) M(5) M(6) M(7) M(8) M(9) \
  M(10) M(11) M(12) M(13) M(14) M(15) M(16) M(17) M(18) M(19) \
  M(20) M(21) M(22) M(23) M(24) M(25) M(26) M(27) M(28) M(29) \
  M(30) M(31) M(32) M(33) M(34) M(35) M(36) M(37) M(38) M(39) \
  M(40) M(41) M(42) M(43) M(44) M(45) M(46) M(47) M(48) M(49) \
  M(50) M(51) M(52) M(53) M(54) M(55) M(56) M(57) M(58) M(59) \
  M(60) M(61) M(62) M(63)

// 256 threads = 4 waves: wv0/wv1 forward items A/B, wv2/wv3 backward A/B.
// Rationale: waves of one workgroup are slotted round-robin onto the CU's 4
// SIMDs -> each issue-bound wave owns a SIMD (R8's 2-wave blocks packed 2
// waves/SIMD and doubled per-step latency).
extern "C" __global__ __launch_bounds__(256, 1)
void crf_kernel(const float* __restrict__ emis,
                const int*   __restrict__ tags,
                const int*   __restrict__ mask,
                const float* __restrict__ startT,
                const float* __restrict__ endT,
                const float* __restrict__ trans,
                float* __restrict__ out)
{
    const int bid  = blockIdx.x;      // 256 blocks, 2 batch items each
    const int tid  = threadIdx.x;
    const int lane = tid & 63;
    const int wv   = tid >> 6;        // 0..3
    const int item = wv & 1;          // 0 = item 2b, 1 = item 2b+1
    const int b    = bid * 2 + item;

    __shared__ __align__(16) float strans[NT * NT];  // Trow lookups
    __shared__ int   spk[2][SEQ];                    // tag | mask<<16, per item
    __shared__ float xu[2][NT], xv[2][NT];           // final u / v per item
    __shared__ float fsc[2][4];                      // spF, M, spB
    __shared__ int   isc[2][4];                      // esumF, ltF, esumB, ltB

    // ---- one-time staging, all 256 threads ----
    {
        const float4* t4 = (const float4*)trans;
        float4* s4 = (float4*)strans;
        #pragma unroll
        for (int k = 0; k < 4; ++k)
            s4[k * 256 + tid] = t4[k * 256 + tid];
    }
    #pragma unroll
    for (int c = 0; c < 2 * SEQ / 256; ++c) {        // both items' spk
        int idx = c * 256 + tid;                     // [0, 2048)
        int it  = idx >> 10;
        int t   = idx & (SEQ - 1);
        int bb  = bid * 2 + it;
        spk[it][t] = (tags[t * BN + bb] & 0xFFFF) | (mask[t * BN + bb] << 16);
    }
    __syncthreads();

    if (wv < 2) {
        // ================= FORWARD: alpha scan, t = 1..HALF =================
#define EFD(i) const float EF##i = __expf(trans[(i) * NT + lane]);
        RPT64(EFD)
#undef EFD
        float em0    = emis[(0 * BN + b) * NT + lane];
        int   tg_p   = spk[item][0] & 0xFFFF;
        float alpha0 = startT[lane] + em0;
        float M = __int_as_float(__builtin_amdgcn_readfirstlane(__float_as_int(alpha0)));
        float u = __expf(alpha0 - M);
        float score = (lane == tg_p) ? alpha0 : 0.0f;
        int   lt    = tg_p;
        int   esum  = 0;

        int   pkC   = spk[item][1];
        float TrowC = strans[tg_p * NT + lane];

        float emA = emis[(1 * BN + b) * NT + lane];
        float emB = emis[(2 * BN + b) * NT + lane];
        float emC = emis[(3 * BN + b) * NT + lane];
        float emD = emis[(4 * BN + b) * NT + lane];

        #pragma unroll 4
        for (int t = 1; t <= HALF; ++t) {
            const float em_t = emA;
            emA = emB; emB = emC; emC = emD;
            int tn = t + 4; if (tn > HALF) tn = HALF;
            emD = emis[(tn * BN + b) * NT + lane];

            const int   pk   = pkC;
            const int   tg_t = pk & 0xFFFF;
            const int   mk_t = pk >> 16;
            const float Trow = TrowC;

            pkC   = spk[item][t + 1];           // spk[HALF+1] exists
            TrowC = strans[tg_t * NT + lane];

            const float w = __expf(em_t);       // off the u-chain

            float a0=0.f,a1=0.f,a2=0.f,a3=0.f,a4=0.f,a5=0.f,a6=0.f,a7=0.f;
            GALL(u, EF)
            const float s  = ((a0+a1)+(a2+a3)) + ((a4+a5)+(a6+a7));
            const float sw = s * w;

            if (mk_t) {                          // wave-uniform
                u = sw;
                if (lane == tg_t) score += em_t + Trow;
                lt = tg_t;
            }
            if ((t & 3) == 0) {                  // deferred exact renorm
                int e = (__builtin_amdgcn_readfirstlane(__float_as_int(u)) >> 23) & 255;
                u = ldexpf(u, 127 - e);
                esum += e - 127;
            }
        }

        float sp = score;
        #pragma unroll
        for (int off = 32; off > 0; off >>= 1) sp += __shfl_xor(sp, off, 64);
        xu[item][lane] = u;
        if (lane == 0) {
            fsc[item][0] = sp; fsc[item][1] = M;
            isc[item][0] = esum; isc[item][1] = lt;
        }
    } else {
        // ================ BACKWARD: v scan, t = 1023..HALF+1 ================
        // v_{t-1}[i] = mk_t ? sum_j E[i][j] * (w_t[j] v_t[j]) : v_t[i]
#define EBD(j) const float EB##j = __expf(trans[lane * NT + (j)]);
        RPT64(EBD)
#undef EBD
        float v = __expf(endT[lane]);           // v_{1023} = f
        float score = 0.0f;
        int   lt = -1;                          // -1 = no masked step seen
        int   esum = 0;

        int pkA = spk[item][SEQ - 1];           // spk[t]
        int pkN = spk[item][SEQ - 2];           // spk[t-1] (gives tg_{t-1})

        float emA = emis[((SEQ - 1) * BN + b) * NT + lane];
        float emB = emis[((SEQ - 2) * BN + b) * NT + lane];
        float emC = emis[((SEQ - 3) * BN + b) * NT + lane];
        float emD = emis[((SEQ - 4) * BN + b) * NT + lane];

        #pragma unroll 4
        for (int t = SEQ - 1; t > HALF; --t) {
            const float em_t = emA;
            emA = emB; emB = emC; emC = emD;
            int tn = t - 4; if (tn < HALF + 1) tn = HALF + 1;
            emD = emis[(tn * BN + b) * NT + lane];

            const int tgc = pkA & 0xFFFF;
            const int mk  = pkA >> 16;
            const int tgp = pkN & 0xFFFF;                      // tg_{t-1}
            const float Trow = strans[tgp * NT + lane];        // early-issue

            pkA = pkN;                                         // prefetch t-1
            int t2 = t - 2; if (t2 < 0) t2 = 0;
            pkN = spk[item][t2];

            const float w = __expf(em_t);                      // off-chain
            const float y = w * v;                             // on-chain

            float a0=0.f,a1=0.f,a2=0.f,a3=0.f,a4=0.f,a5=0.f,a6=0.f,a7=0.f;
            GALL(y, EB)
            const float s = ((a0+a1)+(a2+a3)) + ((a4+a5)+(a6+a7));

            if (mk) {                            // wave-uniform
                v = s;
                if (lane == tgc) score += em_t + Trow;
                if (lt < 0) lt = tgc;            // first seen = highest t
            }
            if ((t & 3) == 0) {                  // deferred exact renorm
                int e = (__builtin_amdgcn_readfirstlane(__float_as_int(v)) >> 23) & 255;
                v = ldexpf(v, 127 - e);
                esum += e - 127;
            }
        }

        float sp = score;
        #pragma unroll
        for (int off = 32; off > 0; off >>= 1) sp += __shfl_xor(sp, off, 64);
        xv[item][lane] = v;
        if (lane == 0) {
            fsc[item][2] = sp;
            isc[item][2] = esum; isc[item][3] = lt;
        }
    }

    __syncthreads();

    // ---- combine: wave 0 -> item 0, wave 1 -> item 1 ----
    if (wv < 2) {
        float prod = xu[item][lane] * xv[item][lane];
        #pragma unroll
        for (int off = 32; off > 0; off >>= 1) prod += __shfl_xor(prod, off, 64);
        if (lane == 0) {
            int   ltB = isc[item][3];
            int   lt  = (ltB >= 0) ? ltB : isc[item][1];
            float sc  = fsc[item][0] + fsc[item][2] + endT[lt];
            float denom = fsc[item][1]
                        + (float)(isc[item][0] + isc[item][2]) * 0.69314718055994531f
                        + __logf(prod);
            atomicAdd(out, sc - denom);
        }
    }
}

extern "C" void kernel_launch(void* const* d_in, const int* in_sizes, int n_in,
                              void* d_out, int out_size, void* d_ws, size_t ws_size,
                              hipStream_t stream)
{
    const float* emis   = (const float*)d_in[0];
    const int*   tags   = (const int*)  d_in[1];
    const int*   mask   = (const int*)  d_in[2];
    const float* startT = (const float*)d_in[3];
    const float* endT   = (const float*)d_in[4];
    const float* trans  = (const float*)d_in[5];
    float* out = (float*)d_out;

    zero_out_kernel<<<1, 1, 0, stream>>>(out);
    crf_kernel<<<dim3(BN / 2), dim3(256), 0, stream>>>(emis, tags, mask,
                                                       startT, endT, trans, out);
}